// Round 13
// baseline (288.415 us; speedup 1.0000x reference)
//
#include <hip/hip_runtime.h>
#include <cstdint>
#include <cstddef>

typedef _Float16 f16;
typedef f16 f16x2 __attribute__((ext_vector_type(2)));
typedef f16 f16x4 __attribute__((ext_vector_type(4)));
typedef f16 f16x8 __attribute__((ext_vector_type(8)));
typedef float f32x4 __attribute__((ext_vector_type(4)));

// Global layouts for GEMM operands are CHUNK-SWIZZLED: within each 64-f16
// K-group of row r, the 8-f16 chunk c is stored at position c^(r&7).
// Staging loads+stores use identity indices (swizzle already in memory);
// fragment reads use the XOR formula (r7-proven conflict-free).

// ---- prep: transposes (0..1023) then x cvt (1024..3071, 8 elems/thread) ----
__global__ __launch_bounds__(256) void k_prep(const float* __restrict__ x,
                                              const float* __restrict__ Wqkv,
                                              const float* __restrict__ Wproj,
                                              f16* __restrict__ Xh,
                                              f16* __restrict__ WqkvT,
                                              f16* __restrict__ WprojT) {
  const int bid = blockIdx.x, t = threadIdx.x;
  if (bid >= 1024) {
    int gid = (bid - 1024) * 256 + t;   // 0..524287
    int r = gid >> 7;                   // row 0..4095
    int c = gid & 127;                  // 8-f16 chunk in row
    int g = c >> 3, cl = c & 7;
    const float* src = x + ((size_t)r << 10) + c * 8;
    float4 u0 = *(const float4*)src;
    float4 u1 = *(const float4*)(src + 4);
    f16x8 hv;
    hv[0] = (f16)u0.x; hv[1] = (f16)u0.y; hv[2] = (f16)u0.z; hv[3] = (f16)u0.w;
    hv[4] = (f16)u1.x; hv[5] = (f16)u1.y; hv[6] = (f16)u1.z; hv[7] = (f16)u1.w;
    *(f16x8*)(Xh + ((size_t)r << 10) + g * 64 + ((cl ^ (r & 7)) * 8)) = hv;
    return;
  }
  const float* in;
  f16* out;
  int N, bx, by;
  if (bid < 768) {
    bx = bid % 48; by = bid / 48; in = Wqkv; out = WqkvT; N = 3072;
  } else {
    int tb = bid - 768;
    bx = tb % 16; by = tb / 16; in = Wproj; out = WprojT; N = 1024;
  }
  const int K = 1024;
  __shared__ float tile[64][65];
  const int xx = t & 63, y0 = t >> 6;
#pragma unroll
  for (int r = 0; r < 16; ++r) {
    int y = y0 + r * 4;
    tile[y][xx] = in[(size_t)(by * 64 + y) * N + bx * 64 + xx];
  }
  __syncthreads();
  const int ch = xx >> 3, off = xx & 7;
#pragma unroll
  for (int r = 0; r < 16; ++r) {
    int y = y0 + r * 4;
    int n = bx * 64 + y;
    out[(size_t)n * K + by * 64 + ((ch ^ (n & 7)) * 8) + off] =
        (f16)tile[xx][y];
  }
}

// ------------- GEMM: C[M][N] = A[M][K] * Bt[N][K]^T  (f16 in, fp32 acc) ----
// Register double-buffer prefetch: kt+1 global loads issued before barrier 2,
// in flight across kt's MFMA phase. __launch_bounds__(256,3) caps VGPR at
// ~170 so the ~144-reg peak (64 acc + 32 prefetch + 32 frag + addr) does NOT
// spill (r5's failure mode). Pre-swizzled globals -> identity staging stores,
// XOR fragment reads, 0 conflicts, 32 KB LDS, full grid 3 blocks/CU.
template <int F32OUT>
__global__ __launch_bounds__(256, 3) void k_gemm_bt(const f16* __restrict__ A,
                                                    const f16* __restrict__ Bt,
                                                    void* __restrict__ Cout,
                                                    int M, int N, int K) {
  __shared__ __align__(16) f16 As[128 * 64];
  __shared__ __align__(16) f16 Bs[128 * 64];
  const int t = threadIdx.x;
  const int m0 = blockIdx.x * 128, n0 = blockIdx.y * 128;
  const int w = t >> 6, l = t & 63, sl = l & 15, quad = l >> 4;
  const int wm = (w & 1) * 64, wn = (w >> 1) * 64;
  f32x4 acc[4][4] = {};
  const int nk = K >> 6;
  uint4 ra[4], rb[4];
#pragma unroll
  for (int c = 0; c < 4; ++c) {
    int cid = t + c * 256;
    int row = cid >> 3, ch = cid & 7;
    ra[c] = *(const uint4*)(A + (size_t)(m0 + row) * K + ch * 8);
    rb[c] = *(const uint4*)(Bt + (size_t)(n0 + row) * K + ch * 8);
  }
  for (int kt = 0; kt < nk; ++kt) {
    __syncthreads();  // previous compute done reading LDS
#pragma unroll
    for (int c = 0; c < 4; ++c) {
      int cid = t + c * 256;
      int row = cid >> 3, ch = cid & 7;
      *(uint4*)(As + row * 64 + ch * 8) = ra[c];
      *(uint4*)(Bs + row * 64 + ch * 8) = rb[c];
    }
    if (kt + 1 < nk) {
#pragma unroll
      for (int c = 0; c < 4; ++c) {
        int cid = t + c * 256;
        int row = cid >> 3, ch = cid & 7;
        ra[c] = *(const uint4*)(A + (size_t)(m0 + row) * K + (kt + 1) * 64 +
                                ch * 8);
        rb[c] = *(const uint4*)(Bt + (size_t)(n0 + row) * K + (kt + 1) * 64 +
                                ch * 8);
      }
    }
    __syncthreads();
#pragma unroll
    for (int kk = 0; kk < 64; kk += 32) {
      const int cb = kk >> 3;
      f16x8 af[4], bfr[4];
#pragma unroll
      for (int mi = 0; mi < 4; ++mi)
        af[mi] = *(const f16x8*)(As + (wm + mi * 16 + sl) * 64 +
                                 (((cb + quad) ^ (sl & 7)) * 8));
#pragma unroll
      for (int ni = 0; ni < 4; ++ni)
        bfr[ni] = *(const f16x8*)(Bs + (wn + ni * 16 + sl) * 64 +
                                  (((cb + quad) ^ (sl & 7)) * 8));
#pragma unroll
      for (int mi = 0; mi < 4; ++mi)
#pragma unroll
        for (int ni = 0; ni < 4; ++ni)
          acc[mi][ni] = __builtin_amdgcn_mfma_f32_16x16x32_f16(
              af[mi], bfr[ni], acc[mi][ni], 0, 0, 0);
    }
  }
#pragma unroll
  for (int mi = 0; mi < 4; ++mi)
#pragma unroll
    for (int ni = 0; ni < 4; ++ni) {
      int row = m0 + wm + mi * 16 + quad * 4;
      int col = n0 + wn + ni * 16 + sl;
#pragma unroll
      for (int r = 0; r < 4; ++r) {
        if (F32OUT)
          ((float*)Cout)[(size_t)(row + r) * N + col] = acc[mi][ni][r];
        else
          ((f16*)Cout)[(size_t)(row + r) * N + col] = (f16)acc[mi][ni][r];
      }
    }
}

// ---------------- MFMA sparse flash attention (r12 version) ----------------
__global__ __launch_bounds__(256) void k_attn(const f16* __restrict__ qkv,
                                              f16* __restrict__ y) {
  constexpr int VT = 226;
  constexpr int KT = 72;
  constexpr int PT = 232;
  __shared__ __align__(16) char smem[224 * KT * 2 + 4 * 16 * PT * 2 + 512];
  f16* Ks = (f16*)smem;
  f16* Vt = (f16*)smem;                  // aliases Ks (phase 3+)
  f16* Pb = (f16*)(smem + 224 * KT * 2);
  float* rmax = (float*)(smem + 224 * KT * 2 + 4 * 16 * PT * 2);
  float* lsum = rmax + 64;

  const int t = threadIdx.x, wv = t >> 6, l = t & 63;
  const int sl = l & 15, quad = l >> 4;
  const int blk = blockIdx.x;
  const int qb = blk & 31;
  const int bh = blk >> 5;
  const int b = bh >> 4, h = bh & 15;
  const f16* base = qkv + (size_t)b * 2048 * 3072;
  const int qc = h * 64, kc = 1024 + h * 64, vc = 2048 + h * 64;

  const int row0 = qb * 64;
  const int hi = row0 + 63;
  int lo = row0 - 127; if (lo < 0) lo = 0;
  const int ng = (lo + 63) >> 6;
  const int T = ng + (hi - lo + 1);
  int NT = (T + 15) >> 4;
  NT = (NT + 1) & ~1;
  const int NC = NT * 16;

  for (int cid = t; cid < NC * 8; cid += 256) {
    int idx = cid >> 3, ch = cid & 7;
    int j = idx < ng ? idx * 64 : lo + idx - ng;
    if (idx >= T) j = lo;
    *(uint4*)(Ks + idx * KT + ch * 8) =
        *(const uint4*)(base + (size_t)j * 3072 + kc + ch * 8);
  }
  const int i0 = row0 + wv * 16;
  f16x8 aq[2];
#pragma unroll
  for (int c = 0; c < 2; ++c) {
    f16x8 qv = *(const f16x8*)(base + (size_t)(i0 + sl) * 3072 + qc + c * 32 +
                               quad * 8);
#pragma unroll
    for (int jj = 0; jj < 8; ++jj) qv[jj] = qv[jj] * (f16)0.125f;
    aq[c] = qv;
  }
  __syncthreads();

  f16* Pw = Pb + wv * 16 * PT;
  float mloc[4] = {-INFINITY, -INFINITY, -INFINITY, -INFINITY};
  for (int kt = 0; kt < NT; ++kt) {
    const int idx = kt * 16 + sl;
    const bool pad = idx >= T;
    int j = idx < ng ? idx * 64 : lo + idx - ng;
    if (pad) j = lo;
    const f16* krow = Ks + idx * KT;
    f16x8 bk0 = *(const f16x8*)(krow + quad * 8);
    f16x8 bk1 = *(const f16x8*)(krow + 32 + quad * 8);
    f32x4 s = {0.f, 0.f, 0.f, 0.f};
    s = __builtin_amdgcn_mfma_f32_16x16x32_f16(aq[0], bk0, s, 0, 0, 0);
    s = __builtin_amdgcn_mfma_f32_16x16x32_f16(aq[1], bk1, s, 0, 0, 0);
#pragma unroll
    for (int r = 0; r < 4; ++r) {
      const int i = i0 + quad * 4 + r;
      const bool ok = !pad && (j <= i) && ((i - j) < 128 || (j & 63) == 0);
      const float sv = ok ? s[r] : -INFINITY;
      mloc[r] = fmaxf(mloc[r], sv);
      Pw[(quad * 4 + r) * PT + idx] = (f16)sv;
    }
  }
#pragma unroll
  for (int off = 1; off < 16; off <<= 1)
#pragma unroll
    for (int r = 0; r < 4; ++r)
      mloc[r] = fmaxf(mloc[r], __shfl_xor(mloc[r], off, 64));
  if (sl == 0)
#pragma unroll
    for (int r = 0; r < 4; ++r) rmax[wv * 16 + quad * 4 + r] = mloc[r];
  __syncthreads();

  for (int cid = t; cid < NC * 8; cid += 256) {
    int idx = cid >> 3, ch = cid & 7;
    int j = idx < ng ? idx * 64 : lo + idx - ng;
    if (idx >= T) j = lo;
    f16x8 v8 = *(const f16x8*)(base + (size_t)j * 3072 + vc + ch * 8);
#pragma unroll
    for (int jj = 0; jj < 8; ++jj) Vt[(ch * 8 + jj) * VT + idx] = v8[jj];
  }
  __syncthreads();

  const int NKC = NC / 32;
  f32x4 o[4] = {};
  float ls = 0.f;
  const float mrow = rmax[wv * 16 + sl];
  for (int kcc = 0; kcc < NKC; ++kcc) {
    f16x8 raw = *(const f16x8*)(Pw + sl * PT + kcc * 32 + quad * 8);
    f16x8 ap;
#pragma unroll
    for (int jj = 0; jj < 8; ++jj) {
      float p = __expf((float)raw[jj] - mrow);
      ls += p;
      ap[jj] = (f16)p;
    }
#pragma unroll
    for (int dt = 0; dt < 4; ++dt) {
      const uint32_t* vb =
          (const uint32_t*)(Vt + (dt * 16 + sl) * VT + kcc * 32 + quad * 8);
      union { uint32_t u[4]; f16x8 v; } cv;
      cv.u[0] = vb[0]; cv.u[1] = vb[1]; cv.u[2] = vb[2]; cv.u[3] = vb[3];
      o[dt] = __builtin_amdgcn_mfma_f32_16x16x32_f16(ap, cv.v, o[dt], 0, 0, 0);
    }
  }
  ls += __shfl_xor(ls, 16, 64);
  ls += __shfl_xor(ls, 32, 64);
  if (quad == 0) lsum[wv * 16 + sl] = ls;
  __syncthreads();
#pragma unroll
  for (int r = 0; r < 4; ++r) {
    const int q = quad * 4 + r;
    const float inv = 1.0f / lsum[wv * 16 + q];
    const int grow = i0 + q;
    const int sw = grow & 7;
    f16* yr = y + (((size_t)b * 2048 + grow) << 10) + h * 64;
    const int off = sl & 7, cbase = sl >> 3;
#pragma unroll
    for (int dt = 0; dt < 4; ++dt) {
      int cg = dt * 2 + cbase;
      yr[((cg ^ sw) * 8) + off] = (f16)(o[dt][r] * inv);
    }
  }
}

extern "C" void kernel_launch(void* const* d_in, const int* in_sizes, int n_in,
                              void* d_out, int out_size, void* d_ws,
                              size_t ws_size, hipStream_t stream) {
  (void)in_sizes; (void)n_in; (void)out_size; (void)ws_size;
  const float* x = (const float*)d_in[0];
  const float* Wqkv = (const float*)d_in[1];
  const float* Wproj = (const float*)d_in[2];
  float* out = (float*)d_out;
  char* ws = (char*)d_ws;
  f16* Xh     = (f16*)(ws);                         // 4096x1024 (swizzled)
  f16* WqkvT  = (f16*)(ws + (size_t)8  * 1048576);  // 3072x1024 (swizzled)
  f16* WprojT = (f16*)(ws + (size_t)14 * 1048576);  // 1024x1024 (swizzled)
  f16* QKV    = (f16*)(ws + (size_t)16 * 1048576);  // 4096x3072 (normal)
  f16* Yh     = (f16*)(ws + (size_t)40 * 1048576);  // 4096x1024 (swizzled)

  k_prep<<<3072, 256, 0, stream>>>(x, Wqkv, Wproj, Xh, WqkvT, WprojT);
  k_gemm_bt<0><<<dim3(32, 24), 256, 0, stream>>>(Xh, WqkvT, (void*)QKV, 4096,
                                                 3072, 1024);
  k_attn<<<1024, 256, 0, stream>>>(QKV, Yh);
  k_gemm_bt<1><<<dim3(32, 8), 256, 0, stream>>>(Yh, WprojT, (void*)out, 4096,
                                                1024, 1024);
}

// Round 14
// 159.515 us; speedup vs baseline: 1.8081x; 1.8081x over previous
//
#include <hip/hip_runtime.h>
#include <cstdint>
#include <cstddef>

typedef _Float16 f16;
typedef f16 f16x2 __attribute__((ext_vector_type(2)));
typedef f16 f16x4 __attribute__((ext_vector_type(4)));
typedef f16 f16x8 __attribute__((ext_vector_type(8)));
typedef float f32x4 __attribute__((ext_vector_type(4)));

// Global layouts for GEMM operands are CHUNK-SWIZZLED: within each 64-f16
// K-group of row r, the 8-f16 chunk c is stored at position c^(r&7).
// GEMM staging is then PURE IDENTITY (load offset == store offset == cid*8);
// fragment reads use the XOR formula (r7-proven conflict-free).

// ---- prep: transposes (0..1023) then x cvt (1024..3071, 8 elems/thread) ----
__global__ __launch_bounds__(256) void k_prep(const float* __restrict__ x,
                                              const float* __restrict__ Wqkv,
                                              const float* __restrict__ Wproj,
                                              f16* __restrict__ Xh,
                                              f16* __restrict__ WqkvT,
                                              f16* __restrict__ WprojT) {
  const int bid = blockIdx.x, t = threadIdx.x;
  if (bid >= 1024) {
    int gid = (bid - 1024) * 256 + t;   // 0..524287
    int r = gid >> 7;                   // row 0..4095
    int c = gid & 127;                  // 8-f16 chunk in row
    int g = c >> 3, cl = c & 7;
    const float* src = x + ((size_t)r << 10) + c * 8;
    float4 u0 = *(const float4*)src;
    float4 u1 = *(const float4*)(src + 4);
    f16x8 hv;
    hv[0] = (f16)u0.x; hv[1] = (f16)u0.y; hv[2] = (f16)u0.z; hv[3] = (f16)u0.w;
    hv[4] = (f16)u1.x; hv[5] = (f16)u1.y; hv[6] = (f16)u1.z; hv[7] = (f16)u1.w;
    *(f16x8*)(Xh + ((size_t)r << 10) + g * 64 + ((cl ^ (r & 7)) * 8)) = hv;
    return;
  }
  const float* in;
  f16* out;
  int N, bx, by;
  if (bid < 768) {
    bx = bid % 48; by = bid / 48; in = Wqkv; out = WqkvT; N = 3072;
  } else {
    int tb = bid - 768;
    bx = tb % 16; by = tb / 16; in = Wproj; out = WprojT; N = 1024;
  }
  const int K = 1024;
  __shared__ float tile[64][65];
  const int xx = t & 63, y0 = t >> 6;
#pragma unroll
  for (int r = 0; r < 16; ++r) {
    int y = y0 + r * 4;
    tile[y][xx] = in[(size_t)(by * 64 + y) * N + bx * 64 + xx];
  }
  __syncthreads();
  const int ch = xx >> 3, off = xx & 7;
#pragma unroll
  for (int r = 0; r < 16; ++r) {
    int y = y0 + r * 4;
    int n = bx * 64 + y;
    out[(size_t)n * K + by * 64 + ((ch ^ (n & 7)) * 8) + off] =
        (f16)tile[xx][y];
  }
}

// ------------- GEMM: C[M][N] = A[M][K] * Bt[N][K]^T  (f16 in, fp32 acc) ----
// r10-proven interleaved register staging (short live ranges, compiler
// hoists globals, NO cross-barrier register buffers — r5/r8/r13 all spilled).
// Pre-swizzled globals make staging identity: zero address VALU.
template <int F32OUT>
__global__ __launch_bounds__(256) void k_gemm_bt(const f16* __restrict__ A,
                                                 const f16* __restrict__ Bt,
                                                 void* __restrict__ Cout,
                                                 int M, int N, int K) {
  __shared__ __align__(16) f16 As[128 * 64];
  __shared__ __align__(16) f16 Bs[128 * 64];
  const int t = threadIdx.x;
  const int m0 = blockIdx.x * 128, n0 = blockIdx.y * 128;
  const int w = t >> 6, l = t & 63, sl = l & 15, quad = l >> 4;
  const int wm = (w & 1) * 64, wn = (w >> 1) * 64;
  f32x4 acc[4][4] = {};
  const int nk = K >> 6;
  // identity staging: thread handles chunks cid = t + c*256; global offset
  // within tile row-block == LDS offset == cid*8 f16.
  const f16* Ab = A + (size_t)m0 * K;   // tile rows are K-contiguous groups
  const f16* Bb = Bt + (size_t)n0 * K;
  for (int kt = 0; kt < nk; ++kt) {
    __syncthreads();
#pragma unroll
    for (int c = 0; c < 4; ++c) {
      int cid = t + c * 256;          // 0..1023
      int row = cid >> 3;             // 0..127
      int o8 = cid * 8 - row * 64;    // = (cid&7)*8, kept linear for addr
      *(uint4*)(As + cid * 8) =
          *(const uint4*)(Ab + (size_t)row * K + kt * 64 + o8);
      *(uint4*)(Bs + cid * 8) =
          *(const uint4*)(Bb + (size_t)row * K + kt * 64 + o8);
    }
    __syncthreads();
#pragma unroll
    for (int kk = 0; kk < 64; kk += 32) {
      const int cb = kk >> 3;
      f16x8 af[4], bfr[4];
#pragma unroll
      for (int mi = 0; mi < 4; ++mi)
        af[mi] = *(const f16x8*)(As + (wm + mi * 16 + sl) * 64 +
                                 (((cb + quad) ^ (sl & 7)) * 8));
#pragma unroll
      for (int ni = 0; ni < 4; ++ni)
        bfr[ni] = *(const f16x8*)(Bs + (wn + ni * 16 + sl) * 64 +
                                  (((cb + quad) ^ (sl & 7)) * 8));
#pragma unroll
      for (int mi = 0; mi < 4; ++mi)
#pragma unroll
        for (int ni = 0; ni < 4; ++ni)
          acc[mi][ni] = __builtin_amdgcn_mfma_f32_16x16x32_f16(
              af[mi], bfr[ni], acc[mi][ni], 0, 0, 0);
    }
  }
#pragma unroll
  for (int mi = 0; mi < 4; ++mi)
#pragma unroll
    for (int ni = 0; ni < 4; ++ni) {
      int row = m0 + wm + mi * 16 + quad * 4;
      int col = n0 + wn + ni * 16 + sl;
#pragma unroll
      for (int r = 0; r < 4; ++r) {
        if (F32OUT)
          ((float*)Cout)[(size_t)(row + r) * N + col] = acc[mi][ni][r];
        else
          ((f16*)Cout)[(size_t)(row + r) * N + col] = (f16)acc[mi][ni][r];
      }
    }
}

// ---------------- MFMA sparse flash attention (r12 version) ----------------
__global__ __launch_bounds__(256) void k_attn(const f16* __restrict__ qkv,
                                              f16* __restrict__ y) {
  constexpr int VT = 226;
  constexpr int KT = 72;
  constexpr int PT = 232;
  __shared__ __align__(16) char smem[224 * KT * 2 + 4 * 16 * PT * 2 + 512];
  f16* Ks = (f16*)smem;
  f16* Vt = (f16*)smem;                  // aliases Ks (phase 3+)
  f16* Pb = (f16*)(smem + 224 * KT * 2);
  float* rmax = (float*)(smem + 224 * KT * 2 + 4 * 16 * PT * 2);
  float* lsum = rmax + 64;

  const int t = threadIdx.x, wv = t >> 6, l = t & 63;
  const int sl = l & 15, quad = l >> 4;
  const int blk = blockIdx.x;
  const int qb = blk & 31;
  const int bh = blk >> 5;
  const int b = bh >> 4, h = bh & 15;
  const f16* base = qkv + (size_t)b * 2048 * 3072;
  const int qc = h * 64, kc = 1024 + h * 64, vc = 2048 + h * 64;

  const int row0 = qb * 64;
  const int hi = row0 + 63;
  int lo = row0 - 127; if (lo < 0) lo = 0;
  const int ng = (lo + 63) >> 6;
  const int T = ng + (hi - lo + 1);
  int NT = (T + 15) >> 4;
  NT = (NT + 1) & ~1;
  const int NC = NT * 16;

  for (int cid = t; cid < NC * 8; cid += 256) {
    int idx = cid >> 3, ch = cid & 7;
    int j = idx < ng ? idx * 64 : lo + idx - ng;
    if (idx >= T) j = lo;
    *(uint4*)(Ks + idx * KT + ch * 8) =
        *(const uint4*)(base + (size_t)j * 3072 + kc + ch * 8);
  }
  const int i0 = row0 + wv * 16;
  f16x8 aq[2];
#pragma unroll
  for (int c = 0; c < 2; ++c) {
    f16x8 qv = *(const f16x8*)(base + (size_t)(i0 + sl) * 3072 + qc + c * 32 +
                               quad * 8);
#pragma unroll
    for (int jj = 0; jj < 8; ++jj) qv[jj] = qv[jj] * (f16)0.125f;
    aq[c] = qv;
  }
  __syncthreads();

  f16* Pw = Pb + wv * 16 * PT;
  float mloc[4] = {-INFINITY, -INFINITY, -INFINITY, -INFINITY};
  for (int kt = 0; kt < NT; ++kt) {
    const int idx = kt * 16 + sl;
    const bool pad = idx >= T;
    int j = idx < ng ? idx * 64 : lo + idx - ng;
    if (pad) j = lo;
    const f16* krow = Ks + idx * KT;
    f16x8 bk0 = *(const f16x8*)(krow + quad * 8);
    f16x8 bk1 = *(const f16x8*)(krow + 32 + quad * 8);
    f32x4 s = {0.f, 0.f, 0.f, 0.f};
    s = __builtin_amdgcn_mfma_f32_16x16x32_f16(aq[0], bk0, s, 0, 0, 0);
    s = __builtin_amdgcn_mfma_f32_16x16x32_f16(aq[1], bk1, s, 0, 0, 0);
#pragma unroll
    for (int r = 0; r < 4; ++r) {
      const int i = i0 + quad * 4 + r;
      const bool ok = !pad && (j <= i) && ((i - j) < 128 || (j & 63) == 0);
      const float sv = ok ? s[r] : -INFINITY;
      mloc[r] = fmaxf(mloc[r], sv);
      Pw[(quad * 4 + r) * PT + idx] = (f16)sv;
    }
  }
#pragma unroll
  for (int off = 1; off < 16; off <<= 1)
#pragma unroll
    for (int r = 0; r < 4; ++r)
      mloc[r] = fmaxf(mloc[r], __shfl_xor(mloc[r], off, 64));
  if (sl == 0)
#pragma unroll
    for (int r = 0; r < 4; ++r) rmax[wv * 16 + quad * 4 + r] = mloc[r];
  __syncthreads();

  for (int cid = t; cid < NC * 8; cid += 256) {
    int idx = cid >> 3, ch = cid & 7;
    int j = idx < ng ? idx * 64 : lo + idx - ng;
    if (idx >= T) j = lo;
    f16x8 v8 = *(const f16x8*)(base + (size_t)j * 3072 + vc + ch * 8);
#pragma unroll
    for (int jj = 0; jj < 8; ++jj) Vt[(ch * 8 + jj) * VT + idx] = v8[jj];
  }
  __syncthreads();

  const int NKC = NC / 32;
  f32x4 o[4] = {};
  float ls = 0.f;
  const float mrow = rmax[wv * 16 + sl];
  for (int kcc = 0; kcc < NKC; ++kcc) {
    f16x8 raw = *(const f16x8*)(Pw + sl * PT + kcc * 32 + quad * 8);
    f16x8 ap;
#pragma unroll
    for (int jj = 0; jj < 8; ++jj) {
      float p = __expf((float)raw[jj] - mrow);
      ls += p;
      ap[jj] = (f16)p;
    }
#pragma unroll
    for (int dt = 0; dt < 4; ++dt) {
      const uint32_t* vb =
          (const uint32_t*)(Vt + (dt * 16 + sl) * VT + kcc * 32 + quad * 8);
      union { uint32_t u[4]; f16x8 v; } cv;
      cv.u[0] = vb[0]; cv.u[1] = vb[1]; cv.u[2] = vb[2]; cv.u[3] = vb[3];
      o[dt] = __builtin_amdgcn_mfma_f32_16x16x32_f16(ap, cv.v, o[dt], 0, 0, 0);
    }
  }
  ls += __shfl_xor(ls, 16, 64);
  ls += __shfl_xor(ls, 32, 64);
  if (quad == 0) lsum[wv * 16 + sl] = ls;
  __syncthreads();
#pragma unroll
  for (int r = 0; r < 4; ++r) {
    const int q = quad * 4 + r;
    const float inv = 1.0f / lsum[wv * 16 + q];
    const int grow = i0 + q;
    const int sw = grow & 7;
    f16* yr = y + (((size_t)b * 2048 + grow) << 10) + h * 64;
    const int off = sl & 7, cbase = sl >> 3;
#pragma unroll
    for (int dt = 0; dt < 4; ++dt) {
      int cg = dt * 2 + cbase;
      yr[((cg ^ sw) * 8) + off] = (f16)(o[dt][r] * inv);
    }
  }
}

extern "C" void kernel_launch(void* const* d_in, const int* in_sizes, int n_in,
                              void* d_out, int out_size, void* d_ws,
                              size_t ws_size, hipStream_t stream) {
  (void)in_sizes; (void)n_in; (void)out_size; (void)ws_size;
  const float* x = (const float*)d_in[0];
  const float* Wqkv = (const float*)d_in[1];
  const float* Wproj = (const float*)d_in[2];
  float* out = (float*)d_out;
  char* ws = (char*)d_ws;
  f16* Xh     = (f16*)(ws);                         // 4096x1024 (swizzled)
  f16* WqkvT  = (f16*)(ws + (size_t)8  * 1048576);  // 3072x1024 (swizzled)
  f16* WprojT = (f16*)(ws + (size_t)14 * 1048576);  // 1024x1024 (swizzled)
  f16* QKV    = (f16*)(ws + (size_t)16 * 1048576);  // 4096x3072 (normal)
  f16* Yh     = (f16*)(ws + (size_t)40 * 1048576);  // 4096x1024 (swizzled)

  k_prep<<<3072, 256, 0, stream>>>(x, Wqkv, Wproj, Xh, WqkvT, WprojT);
  k_gemm_bt<0><<<dim3(32, 24), 256, 0, stream>>>(Xh, WqkvT, (void*)QKV, 4096,
                                                 3072, 1024);
  k_attn<<<1024, 256, 0, stream>>>(QKV, Yh);
  k_gemm_bt<1><<<dim3(32, 8), 256, 0, stream>>>(Yh, WprojT, (void*)out, 4096,
                                                1024, 1024);
}